// Round 1
// baseline (773.674 us; speedup 1.0000x reference)
//
#include <hip/hip_runtime.h>
#include <math.h>

#define NBATCH 16
#define CH 64
#define HID 16

// ---------------------------------------------------------------------------
// Kernel 1: segment sums + counts. batch_idx is sorted, so each lane keeps a
// local accumulator for its current batch and flushes on batch change / end.
// Layout: wave of 64 lanes covers 4 consecutive rows; lane = (sub-row<<4)|q,
// q = which float4 (4 channels) of the 64-channel row. A wave load is 1 KiB
// contiguous (16B/lane) -> perfectly coalesced.
// ---------------------------------------------------------------------------
__global__ __launch_bounds__(256) void seg_sum_kernel(
    const float4* __restrict__ feats4,   // [N*16]
    const int*    __restrict__ bidx,     // [N]
    float*        __restrict__ sums,     // [NBATCH*CH]
    float*        __restrict__ counts,   // [NBATCH]
    int n_rows)
{
    const int tid   = blockIdx.x * blockDim.x + threadIdx.x;
    const int wave  = tid >> 6;
    const int lane  = tid & 63;
    const int total_waves = (gridDim.x * blockDim.x) >> 6;

    const int n_groups = (n_rows + 3) >> 2;               // groups of 4 rows
    const int per_wave = (n_groups + total_waves - 1) / total_waves;
    const int g0 = wave * per_wave;
    const int g1 = min(g0 + per_wave, n_groups);

    const int sub = lane >> 4;   // row within group (0..3)
    const int q   = lane & 15;   // float4 slot within row (0..15)

    float4 acc = make_float4(0.f, 0.f, 0.f, 0.f);
    float  cnt = 0.f;
    int    cur_b = -1;

    for (int g = g0; g < g1; ++g) {
        const int row = (g << 2) + sub;
        if (row >= n_rows) break;
        const int b = bidx[row];
        if (b != cur_b) {
            if (cur_b >= 0) {
                float* s = &sums[cur_b * CH + q * 4];
                atomicAdd(s + 0, acc.x);
                atomicAdd(s + 1, acc.y);
                atomicAdd(s + 2, acc.z);
                atomicAdd(s + 3, acc.w);
                if (q == 0 && sub == 0) { /* count flushed below */ }
                if (q == 0) atomicAdd(&counts[cur_b], cnt);
                acc = make_float4(0.f, 0.f, 0.f, 0.f);
                cnt = 0.f;
            }
            cur_b = b;
        }
        const float4 v = feats4[row * 16 + q];
        acc.x += v.x; acc.y += v.y; acc.z += v.z; acc.w += v.w;
        if (q == 0) cnt += 1.f;
    }
    if (cur_b >= 0) {
        float* s = &sums[cur_b * CH + q * 4];
        atomicAdd(s + 0, acc.x);
        atomicAdd(s + 1, acc.y);
        atomicAdd(s + 2, acc.z);
        atomicAdd(s + 3, acc.w);
        if (q == 0) atomicAdd(&counts[cur_b], cnt);
    }
}

// ---------------------------------------------------------------------------
// Kernel 2: tiny SE MLP on one block of 1024 threads.
// mean = sums/max(counts,1); h = relu(mean@W1+b1); gate = sigmoid(h@W2+b2)
// ---------------------------------------------------------------------------
__global__ __launch_bounds__(1024) void mlp_kernel(
    const float* __restrict__ sums,    // [NBATCH*CH]
    const float* __restrict__ counts,  // [NBATCH]
    const float* __restrict__ W1,      // [CH*HID]
    const float* __restrict__ b1,      // [HID]
    const float* __restrict__ W2,      // [HID*CH]
    const float* __restrict__ b2,      // [CH]
    float*       __restrict__ gate)    // [NBATCH*CH]
{
    __shared__ float mean_s[NBATCH * CH];
    __shared__ float h_s[NBATCH * HID];
    __shared__ float inv_s[NBATCH];
    const int tid = threadIdx.x;   // 0..1023

    if (tid < NBATCH) inv_s[tid] = 1.0f / fmaxf(counts[tid], 1.0f);
    __syncthreads();

    mean_s[tid] = sums[tid] * inv_s[tid >> 6];
    __syncthreads();

    if (tid < NBATCH * HID) {
        const int b = tid >> 4, j = tid & 15;
        float acc = b1[j];
        #pragma unroll
        for (int c = 0; c < CH; ++c) acc += mean_s[b * CH + c] * W1[c * HID + j];
        h_s[tid] = fmaxf(acc, 0.f);
    }
    __syncthreads();

    {
        const int b = tid >> 6, ch = tid & 63;
        float acc = b2[ch];
        #pragma unroll
        for (int j = 0; j < HID; ++j) acc += h_s[b * HID + j] * W2[j * CH + ch];
        gate[tid] = 1.0f / (1.0f + expf(-acc));
    }
}

// ---------------------------------------------------------------------------
// Kernel 3: out = feats * gate[batch_idx], float4-vectorized grid-stride.
// ---------------------------------------------------------------------------
__global__ __launch_bounds__(256) void apply_kernel(
    const float4* __restrict__ feats4,  // [N*16]
    const int*    __restrict__ bidx,    // [N]
    const float4* __restrict__ gate4,   // [NBATCH*16]
    float4*       __restrict__ out4,    // [N*16]
    int n4)
{
    const int stride = gridDim.x * blockDim.x;
    for (int i = blockIdx.x * blockDim.x + threadIdx.x; i < n4; i += stride) {
        const int row = i >> 4;
        const int q   = i & 15;
        const int b   = bidx[row];
        const float4 v = feats4[i];
        const float4 g = gate4[b * 16 + q];
        out4[i] = make_float4(v.x * g.x, v.y * g.y, v.z * g.z, v.w * g.w);
    }
}

extern "C" void kernel_launch(void* const* d_in, const int* in_sizes, int n_in,
                              void* d_out, int out_size, void* d_ws, size_t ws_size,
                              hipStream_t stream) {
    const float* feats = (const float*)d_in[0];
    const int*   bidx  = (const int*)d_in[1];
    const float* W1    = (const float*)d_in[2];
    const float* b1    = (const float*)d_in[3];
    const float* W2    = (const float*)d_in[4];
    const float* b2    = (const float*)d_in[5];
    float* out = (float*)d_out;

    const int n_rows = in_sizes[1];          // N
    const int n4     = n_rows * (CH / 4);    // number of float4 elements

    // workspace layout: sums[16*64] | counts[16] | gate[16*64]
    float* sums   = (float*)d_ws;
    float* counts = sums + NBATCH * CH;
    float* gate   = counts + NBATCH;

    hipMemsetAsync(d_ws, 0, (NBATCH * CH + NBATCH) * sizeof(float), stream);

    seg_sum_kernel<<<2048, 256, 0, stream>>>(
        (const float4*)feats, bidx, sums, counts, n_rows);

    mlp_kernel<<<1, 1024, 0, stream>>>(sums, counts, W1, b1, W2, b2, gate);

    apply_kernel<<<2048, 256, 0, stream>>>(
        (const float4*)feats, bidx, (const float4*)gate, (float4*)out, n4);
}

// Round 2
// 371.653 us; speedup vs baseline: 2.0817x; 2.0817x over previous
//
#include <hip/hip_runtime.h>
#include <math.h>

#define NBATCH 16
#define CH 64
#define HID 16

#define P1_BLOCKS  1024
#define P1_THREADS 512
#define RED_CHUNK  32               // partial-blocks per reduce block
#define RED_BLOCKS (P1_BLOCKS / RED_CHUNK)

// ---------------------------------------------------------------------------
// Pass 1: per-block partial segment sums.
// Grid-stride sweep (same access pattern as apply_kernel, which measured
// ~7.9 TB/s effective). stride % 16 == 0 so each thread owns a fixed
// float4-slot q of the 64-channel row. batch_idx is sorted -> cur_b changes
// rarely; flush goes to LDS (cheap), block partial written non-atomically.
// ---------------------------------------------------------------------------
__global__ __launch_bounds__(P1_THREADS) void seg_partial_kernel(
    const float4* __restrict__ feats4,   // [N*16]
    const int*    __restrict__ bidx,     // [N]
    float*        __restrict__ partials, // [P1_BLOCKS * NBATCH*CH]
    int n_rows)
{
    __shared__ float lds[NBATCH * CH];
    const int tid = threadIdx.x;
    for (int j = tid; j < NBATCH * CH; j += P1_THREADS) lds[j] = 0.f;
    __syncthreads();

    const int n4     = n_rows * 16;
    const int stride = gridDim.x * blockDim.x;      // 524288, multiple of 16
    int       i      = blockIdx.x * blockDim.x + tid;
    const int q      = i & 15;                      // fixed per thread

    float4 acc = make_float4(0.f, 0.f, 0.f, 0.f);
    int cur_b = -1;

    for (; i < n4; i += stride) {
        const int row = i >> 4;
        const int b   = bidx[row];
        const float4 v = feats4[i];                 // issued before branch
        if (b != cur_b) {
            if (cur_b >= 0) {
                float* s = &lds[cur_b * CH + q * 4];
                atomicAdd(s + 0, acc.x);
                atomicAdd(s + 1, acc.y);
                atomicAdd(s + 2, acc.z);
                atomicAdd(s + 3, acc.w);
            }
            acc = make_float4(0.f, 0.f, 0.f, 0.f);
            cur_b = b;
        }
        acc.x += v.x; acc.y += v.y; acc.z += v.z; acc.w += v.w;
    }
    if (cur_b >= 0) {
        float* s = &lds[cur_b * CH + q * 4];
        atomicAdd(s + 0, acc.x);
        atomicAdd(s + 1, acc.y);
        atomicAdd(s + 2, acc.z);
        atomicAdd(s + 3, acc.w);
    }
    __syncthreads();

    float4*       p4 = (float4*)(partials + (size_t)blockIdx.x * (NBATCH * CH));
    const float4* l4 = (const float4*)lds;
    for (int j = tid; j < NBATCH * CH / 4; j += P1_THREADS) p4[j] = l4[j];
}

// ---------------------------------------------------------------------------
// Pass 2: reduce partials -> sums. 32 blocks x 256 threads; each thread owns
// one float4 of the 1024-float sum vector; 32 atomics per address total.
// ---------------------------------------------------------------------------
__global__ __launch_bounds__(256) void reduce_kernel(
    const float4* __restrict__ partials4,  // [P1_BLOCKS*256]
    float*        __restrict__ sums)       // [NBATCH*CH]
{
    const int tid  = threadIdx.x;          // 0..255
    const int base = blockIdx.x * RED_CHUNK;
    float4 acc = make_float4(0.f, 0.f, 0.f, 0.f);
    #pragma unroll 8
    for (int k = 0; k < RED_CHUNK; ++k) {
        const float4 v = partials4[(size_t)(base + k) * 256 + tid];
        acc.x += v.x; acc.y += v.y; acc.z += v.z; acc.w += v.w;
    }
    float* s = &sums[tid * 4];
    atomicAdd(s + 0, acc.x);
    atomicAdd(s + 1, acc.y);
    atomicAdd(s + 2, acc.z);
    atomicAdd(s + 3, acc.w);
}

// ---------------------------------------------------------------------------
// Pass 3: tiny SE MLP, one block. Counts via 17 binary searches on the
// sorted batch_idx (removes count tracking from the hot pass).
// ---------------------------------------------------------------------------
__global__ __launch_bounds__(1024) void mlp_kernel(
    const float* __restrict__ sums,    // [NBATCH*CH]
    const int*   __restrict__ bidx,    // [N], sorted
    int n_rows,
    const float* __restrict__ W1,      // [CH*HID]
    const float* __restrict__ b1,      // [HID]
    const float* __restrict__ W2,      // [HID*CH]
    const float* __restrict__ b2,      // [CH]
    float*       __restrict__ gate)    // [NBATCH*CH]
{
    __shared__ float mean_s[NBATCH * CH];
    __shared__ float h_s[NBATCH * HID];
    __shared__ int   boundary[NBATCH + 1];
    const int tid = threadIdx.x;   // 0..1023

    if (tid <= NBATCH) {
        if (tid == NBATCH) {
            boundary[tid] = n_rows;
        } else {
            int lo = 0, hi = n_rows;           // first idx with bidx[idx] >= tid
            while (lo < hi) {
                const int mid = (lo + hi) >> 1;
                if (bidx[mid] < tid) lo = mid + 1; else hi = mid;
            }
            boundary[tid] = lo;
        }
    }
    __syncthreads();

    {
        const int b = tid >> 6;
        const float cnt = (float)(boundary[b + 1] - boundary[b]);
        mean_s[tid] = sums[tid] / fmaxf(cnt, 1.0f);
    }
    __syncthreads();

    if (tid < NBATCH * HID) {
        const int b = tid >> 4, j = tid & 15;
        float acc = b1[j];
        #pragma unroll
        for (int c = 0; c < CH; ++c) acc += mean_s[b * CH + c] * W1[c * HID + j];
        h_s[tid] = fmaxf(acc, 0.f);
    }
    __syncthreads();

    {
        const int b = tid >> 6, ch = tid & 63;
        float acc = b2[ch];
        #pragma unroll
        for (int j = 0; j < HID; ++j) acc += h_s[b * HID + j] * W2[j * CH + ch];
        gate[tid] = 1.0f / (1.0f + expf(-acc));
    }
}

// ---------------------------------------------------------------------------
// Pass 4: out = feats * gate[batch_idx], float4 grid-stride (unchanged).
// ---------------------------------------------------------------------------
__global__ __launch_bounds__(256) void apply_kernel(
    const float4* __restrict__ feats4,
    const int*    __restrict__ bidx,
    const float4* __restrict__ gate4,
    float4*       __restrict__ out4,
    int n4)
{
    const int stride = gridDim.x * blockDim.x;
    for (int i = blockIdx.x * blockDim.x + threadIdx.x; i < n4; i += stride) {
        const int row = i >> 4;
        const int q   = i & 15;
        const int b   = bidx[row];
        const float4 v = feats4[i];
        const float4 g = gate4[b * 16 + q];
        out4[i] = make_float4(v.x * g.x, v.y * g.y, v.z * g.z, v.w * g.w);
    }
}

extern "C" void kernel_launch(void* const* d_in, const int* in_sizes, int n_in,
                              void* d_out, int out_size, void* d_ws, size_t ws_size,
                              hipStream_t stream) {
    const float* feats = (const float*)d_in[0];
    const int*   bidx  = (const int*)d_in[1];
    const float* W1    = (const float*)d_in[2];
    const float* b1    = (const float*)d_in[3];
    const float* W2    = (const float*)d_in[4];
    const float* b2    = (const float*)d_in[5];
    float* out = (float*)d_out;

    const int n_rows = in_sizes[1];
    const int n4     = n_rows * (CH / 4);

    // ws layout: sums[1024] | gate[1024] | partials[P1_BLOCKS*1024]
    float* sums = (float*)d_ws;
    float* gate = sums + NBATCH * CH;
    const size_t need = (size_t)(2 * NBATCH * CH + P1_BLOCKS * NBATCH * CH) * sizeof(float);
    // fallback: stash partials in d_out (fully overwritten by apply_kernel)
    float* partials = (ws_size >= need) ? (gate + NBATCH * CH) : (float*)d_out;

    hipMemsetAsync(sums, 0, NBATCH * CH * sizeof(float), stream);

    seg_partial_kernel<<<P1_BLOCKS, P1_THREADS, 0, stream>>>(
        (const float4*)feats, bidx, partials, n_rows);

    reduce_kernel<<<RED_BLOCKS, 256, 0, stream>>>(
        (const float4*)partials, sums);

    mlp_kernel<<<1, 1024, 0, stream>>>(
        sums, bidx, n_rows, W1, b1, W2, b2, gate);

    apply_kernel<<<2048, 256, 0, stream>>>(
        (const float4*)feats, bidx, (const float4*)gate, (float4*)out, n4);
}